// Round 12
// baseline (108.555 us; speedup 1.0000x reference)
//
#include <hip/hip_runtime.h>

#define MTOK 8192   // B*S tokens
#define ED   1024   // E == D == 1024

typedef short s16x8 __attribute__((ext_vector_type(8)));
typedef float f32x4 __attribute__((ext_vector_type(4)));
typedef int   i32x4 __attribute__((ext_vector_type(4)));
typedef unsigned short u16x4 __attribute__((ext_vector_type(4)));

__device__ __forceinline__ int cvtpk(float a, float b) {
    int r;
    asm("v_cvt_pk_bf16_f32 %0, %1, %2" : "=v"(r) : "v"(a), "v"(b));
    return r;
}

// pack f0|f1 (8 fp32) -> 8 bf16 hi + 8 bf16 lo (exact residual), 16B each
__device__ __forceinline__ void cvt_write(void* dstHi, void* dstLo,
                                          const float4 f0, const float4 f1) {
    i32x4 h, l;
    h[0] = cvtpk(f0.x, f0.y); h[1] = cvtpk(f0.z, f0.w);
    h[2] = cvtpk(f1.x, f1.y); h[3] = cvtpk(f1.z, f1.w);
    l[0] = cvtpk(f0.x - __builtin_bit_cast(float, h[0] << 16),
                 f0.y - __builtin_bit_cast(float, h[0] & 0xffff0000));
    l[1] = cvtpk(f0.z - __builtin_bit_cast(float, h[1] << 16),
                 f0.w - __builtin_bit_cast(float, h[1] & 0xffff0000));
    l[2] = cvtpk(f1.x - __builtin_bit_cast(float, h[2] << 16),
                 f1.y - __builtin_bit_cast(float, h[2] & 0xffff0000));
    l[3] = cvtpk(f1.z - __builtin_bit_cast(float, h[3] << 16),
                 f1.w - __builtin_bit_cast(float, h[3] & 0xffff0000));
    *(i32x4*)dstHi = h;
    *(i32x4*)dstLo = l;
}

// ---------------- M -> fragment-major bf16 hi/lo (used for BOTH X and W) ------
// frag[rowblk][kstep][lane][8]: lane (fg=l>>4, fr=l&15) holds
//   M[rowblk*16+fr][kstep*32+fg*8 .. +8]
// == exactly the per-lane MFMA operand bytes (HW-verified via r11's B path).
__global__ __launch_bounds__(256) void frag_kernel(
        const float* __restrict__ M,
        unsigned short* __restrict__ Fhi, unsigned short* __restrict__ Flo) {
    const int task = blockIdx.x * 4 + (threadIdx.x >> 6);
    const int lane = threadIdx.x & 63;
    const int rowblk = task >> 5;
    const int kstep  = task & 31;
    const float* src = M + (size_t)(rowblk * 16 + (lane & 15)) * ED
                         + kstep * 32 + (lane >> 4) * 8;
    const float4 f0 = *(const float4*)src;
    const float4 f1 = *(const float4*)(src + 4);
    const size_t o = ((size_t)task * 64 + lane) * 8;
    cvt_write(&Fhi[o], &Flo[o], f0, f1);
}

// ---------------- frag-direct MFMA GEMM: C[M,E] = X[M,D] * W[E,D]^T -----------
// NO LDS, NO barriers, NO waitcnt asm: both operands fragment-major in global
// (L3-resident), loaded straight to registers, double-buffered 2 K-steps.
// Addressing is SGPR-uniform base + lane*16 voffset. Pure dataflow -> the
// compiler software-pipelines with counted vmcnt on its own (no barrier to
// defeat it). L1 demand: 32KB distinct/block-step over ~1862cyc MFMA = 69 B/cyc
// < 128 B/cyc cap. MFMA floor 24.8 us at the 16x16 rate.
__global__ __launch_bounds__(256, 2) void gemm_frag_kernel(
        const unsigned short* __restrict__ Ahi, const unsigned short* __restrict__ Alo,
        const unsigned short* __restrict__ Bhi, const unsigned short* __restrict__ Blo,
        float* __restrict__ C) {
    // bm-major XCD swizzle: each XCD owns 8 consecutive bm strips (A 4MB octet)
    const int bid = blockIdx.x;
    const int xcd = bid & 7;
    const int j   = bid >> 3;
    const int bm  = xcd * 8 + (j >> 3);   // 0..63
    const int bn  = j & 7;                // 0..7

    const int lane = threadIdx.x & 63;
    const int wid  = threadIdx.x >> 6;
    const int wm = wid >> 1, wn = wid & 1;

    // frag element offset for (rb, t): rb*16384 + t*512 + lane*8  (elems)
    const size_t laneo = (size_t)lane * 8;
    const unsigned short* gAh = Ahi + (size_t)(bm * 8 + wm * 4) * 16384 + laneo;
    const unsigned short* gAl = Alo + (size_t)(bm * 8 + wm * 4) * 16384 + laneo;
    const unsigned short* gBh = Bhi + (size_t)(bn * 8 + wn * 4) * 16384 + laneo;
    const unsigned short* gBl = Blo + (size_t)(bn * 8 + wn * 4) * 16384 + laneo;

    s16x8 ah0[4], al0[4], bh0[4], bl0[4];
    s16x8 ah1[4], al1[4], bh1[4], bl1[4];

#define LOADSET(S, T)                                                  \
    _Pragma("unroll")                                                  \
    for (int i = 0; i < 4; ++i) {                                      \
        ah##S[i] = *(const s16x8*)(gAh + i * 16384 + (T) * 512);       \
        al##S[i] = *(const s16x8*)(gAl + i * 16384 + (T) * 512);       \
        bh##S[i] = *(const s16x8*)(gBh + i * 16384 + (T) * 512);       \
        bl##S[i] = *(const s16x8*)(gBl + i * 16384 + (T) * 512);       \
    }

#define MFMASET(S)                                                     \
    _Pragma("unroll")                                                  \
    for (int i = 0; i < 4; ++i)                                        \
        _Pragma("unroll")                                              \
        for (int jj = 0; jj < 4; ++jj) {                               \
            acc[i][jj] = __builtin_amdgcn_mfma_f32_16x16x32_bf16(ah##S[i], bh##S[jj], acc[i][jj], 0, 0, 0); \
            acc[i][jj] = __builtin_amdgcn_mfma_f32_16x16x32_bf16(ah##S[i], bl##S[jj], acc[i][jj], 0, 0, 0); \
            acc[i][jj] = __builtin_amdgcn_mfma_f32_16x16x32_bf16(al##S[i], bh##S[jj], acc[i][jj], 0, 0, 0); \
        }

    f32x4 acc[4][4] = {};

    LOADSET(0, 0);
    for (int t2 = 0; t2 < 32; t2 += 2) {
        LOADSET(1, t2 + 1);                  // always valid: t2+1 <= 31
        MFMASET(0);
        if (t2 + 2 < 32) LOADSET(0, t2 + 2);
        MFMASET(1);
    }
#undef LOADSET
#undef MFMASET

    const int fr = lane & 15, fg = lane >> 4;
    const int crow = bm * 128 + wm * 64 + fg * 4;
    const int ccol = bn * 128 + wn * 64 + fr;
#pragma unroll
    for (int i = 0; i < 4; ++i)
#pragma unroll
        for (int jj = 0; jj < 4; ++jj)
#pragma unroll
            for (int r = 0; r < 4; ++r)
                C[(size_t)(crow + i * 16 + r) * ED + ccol + jj * 16] = acc[i][jj][r];
}

// ---------------- fp32 fallback GEMM ----------------
#define BM 128
#define BN 128
#define BK 32
#define LDA (BM + 4)
#define LDB (BN + 4)

__global__ __launch_bounds__(256) void gemm_logits_kernel(const float* __restrict__ X,
                                                          const float* __restrict__ W,
                                                          float* __restrict__ C) {
    __shared__ float As[BK][LDA];
    __shared__ float Bs[BK][LDB];
    const int bm  = blockIdx.y * BM;
    const int bn  = blockIdx.x * BN;
    const int tid = threadIdx.x;
    const int tx  = tid & 15;
    const int ty  = tid >> 4;
    const int lr  = tid >> 3;
    const int lc  = (tid & 7) << 2;

    float acc[8][8];
#pragma unroll
    for (int i = 0; i < 8; ++i)
#pragma unroll
        for (int j = 0; j < 8; ++j) acc[i][j] = 0.f;

    for (int k0 = 0; k0 < ED; k0 += BK) {
#pragma unroll
        for (int i = 0; i < 4; ++i) {
            const int r = lr + i * 32;
            float4 va = *(const float4*)&X[(size_t)(bm + r) * ED + k0 + lc];
            As[lc + 0][r] = va.x; As[lc + 1][r] = va.y;
            As[lc + 2][r] = va.z; As[lc + 3][r] = va.w;
            float4 vb = *(const float4*)&W[(size_t)(bn + r) * ED + k0 + lc];
            Bs[lc + 0][r] = vb.x; Bs[lc + 1][r] = vb.y;
            Bs[lc + 2][r] = vb.z; Bs[lc + 3][r] = vb.w;
        }
        __syncthreads();
#pragma unroll
        for (int kk = 0; kk < BK; ++kk) {
            float a[8], b[8];
            *(float4*)&a[0] = *(const float4*)&As[kk][ty * 8];
            *(float4*)&a[4] = *(const float4*)&As[kk][ty * 8 + 4];
            *(float4*)&b[0] = *(const float4*)&Bs[kk][tx * 8];
            *(float4*)&b[4] = *(const float4*)&Bs[kk][tx * 8 + 4];
#pragma unroll
            for (int i = 0; i < 8; ++i)
#pragma unroll
                for (int j = 0; j < 8; ++j)
                    acc[i][j] = fmaf(a[i], b[j], acc[i][j]);
        }
        __syncthreads();
    }
#pragma unroll
    for (int i = 0; i < 8; ++i) {
        const int r = bm + ty * 8 + i;
        float4* dst = (float4*)&C[(size_t)r * ED + bn + tx * 8];
        dst[0] = make_float4(acc[i][0], acc[i][1], acc[i][2], acc[i][3]);
        dst[1] = make_float4(acc[i][4], acc[i][5], acc[i][6], acc[i][7]);
    }
}

__device__ __forceinline__ bool better(float v, int i, float bv, int bi) {
    return (v > bv) || (v == bv && i < bi);
}

// ------------- one wave per token, barrier-free softmax/top2/y -------------
__global__ __launch_bounds__(256, 8) void softmax_wave_kernel(
        const float* __restrict__ X, float* __restrict__ OUT,
        float* __restrict__ partial, int* __restrict__ counts) {
    __shared__ float L[4 * 1024];
    const int tid  = threadIdx.x;
    const int lane = tid & 63;
    const int w    = tid >> 6;
    const int t    = blockIdx.x * 4 + w;          // token

    const float4* row4 = (const float4*)&OUT[(size_t)t * ED];
    float4 p[4];
#pragma unroll
    for (int i = 0; i < 4; ++i) p[i] = row4[lane + 64 * i];  // elem e = 256i+4*lane+c

    float v1 = -1e30f, v2 = -1e30f; int i1 = 0x7fffffff, i2 = 0x7fffffff;
#pragma unroll
    for (int i = 0; i < 4; ++i) {
        const float vv[4] = {p[i].x, p[i].y, p[i].z, p[i].w};
#pragma unroll
        for (int c = 0; c < 4; ++c) {
            const int e = 256 * i + 4 * lane + c;
            const float v = vv[c];
            if (better(v, e, v1, i1)) { v2 = v1; i2 = i1; v1 = v; i1 = e; }
            else if (better(v, e, v2, i2)) { v2 = v; i2 = e; }
        }
    }
#pragma unroll
    for (int off = 32; off; off >>= 1) {
        const float ov1 = __shfl_xor(v1, off); const int oi1 = __shfl_xor(i1, off);
        const float ov2 = __shfl_xor(v2, off); const int oi2 = __shfl_xor(i2, off);
        if (better(ov1, oi1, v1, i1)) {
            float nv2; int ni2;
            if (better(v1, i1, ov2, oi2)) { nv2 = v1; ni2 = i1; }
            else { nv2 = ov2; ni2 = oi2; }
            v1 = ov1; i1 = oi1; v2 = nv2; i2 = ni2;
        } else if (better(ov1, oi1, v2, i2)) { v2 = ov1; i2 = oi1; }
    }
    const float m = v1;   // top1 value IS the row max

    float s = 0.f;
#pragma unroll
    for (int i = 0; i < 4; ++i) {
        p[i].x = __expf(p[i].x - m); p[i].y = __expf(p[i].y - m);
        p[i].z = __expf(p[i].z - m); p[i].w = __expf(p[i].w - m);
        s += p[i].x + p[i].y + p[i].z + p[i].w;
    }
#pragma unroll
    for (int off = 32; off; off >>= 1) s += __shfl_xor(s, off);
    const float inv = 1.f / s;

#pragma unroll
    for (int i = 0; i < 4; ++i) {
        float4 q = make_float4(p[i].x * inv, p[i].y * inv, p[i].z * inv, p[i].w * inv);
        *(float4*)&L[w * 1024 + i * 256 + lane * 4] = q;
    }

    const float p1 = inv;                   // exp(v1-m)=1
    const float p2 = __expf(v2 - m) * inv;
    const int b = t >> 10;
    const float4* x1 = (const float4*)&X[((size_t)(b << 10) + i1) * ED];
    const float4* x2 = (const float4*)&X[((size_t)(b << 10) + i2) * ED];
    float4* yrow = (float4*)&OUT[(size_t)t * ED];
#pragma unroll
    for (int i = 0; i < 4; ++i) {
        const int idx = lane + 64 * i;
        const float4 a = x1[idx];
        const float4 c = x2[idx];
        float4 r;
        r.x = fmaf(p1, a.x, p2 * c.x);
        r.y = fmaf(p1, a.y, p2 * c.y);
        r.z = fmaf(p1, a.z, p2 * c.z);
        r.w = fmaf(p1, a.w, p2 * c.w);
        yrow[idx] = r;
    }

    if (lane == 0) { atomicAdd(&counts[i1], 1); atomicAdd(&counts[i2], 1); }

    __syncthreads();
    float4 s0 = *(float4*)&L[0 * 1024 + tid * 4];
    float4 s1 = *(float4*)&L[1 * 1024 + tid * 4];
    float4 s2 = *(float4*)&L[2 * 1024 + tid * 4];
    float4 s3 = *(float4*)&L[3 * 1024 + tid * 4];
    float4 r;
    r.x = (s0.x + s1.x) + (s2.x + s3.x);
    r.y = (s0.y + s1.y) + (s2.y + s3.y);
    r.z = (s0.z + s1.z) + (s2.z + s3.z);
    r.w = (s0.w + s1.w) + (s2.w + s3.w);
    *(float4*)&partial[(size_t)blockIdx.x * 1024 + tid * 4] = r;
}

// ---------------- aux: deterministic two-stage reduction ----------------
__global__ __launch_bounds__(256) void aux1_kernel(const float* __restrict__ partial,
                                                   const int* __restrict__ counts,
                                                   float* __restrict__ dotPartial) {
    __shared__ float red[16][16];
    const int tid = threadIdx.x;
    const int el  = tid & 15;
    const int ch  = tid >> 4;
    const int e   = blockIdx.x * 16 + el;
    float s = 0.f;
    for (int k = 0; k < 128; ++k)
        s += partial[(size_t)(ch * 128 + k) * 1024 + e];
    red[ch][el] = s;
    __syncthreads();
    if (tid < 16) {
        float rs = 0.f;
#pragma unroll
        for (int c = 0; c < 16; ++c) rs += red[c][tid];
        float val = rs * (float)counts[blockIdx.x * 16 + tid];
#pragma unroll
        for (int off = 8; off; off >>= 1) val += __shfl_xor(val, off);
        if (tid == 0) dotPartial[blockIdx.x] = val;
    }
}

__global__ void aux2_kernel(const float* __restrict__ dotPartial, float* __restrict__ out) {
    const int lane = threadIdx.x;
    float v = dotPartial[lane];
#pragma unroll
    for (int off = 32; off; off >>= 1) v += __shfl_xor(v, off);
    if (lane == 0)
        out[(size_t)MTOK * ED] = v * (0.01f * 1024.f / (8192.f * 16384.f));
}

// ---------------- fallback softmax (proven round-1 path) ----------------
#define TOKS_PER_BLK 16
__global__ __launch_bounds__(256) void softmax_topk_y_kernel(
        const float* __restrict__ X, float* __restrict__ OUT,
        float* __restrict__ router_sum, int* __restrict__ counts) {
    __shared__ float routerLocal[ED];
    __shared__ float redMax[4];
    __shared__ float redSum[4];
    __shared__ float wV1[4]; __shared__ int wI1[4];
    __shared__ float wV2[4]; __shared__ int wI2[4];

    const int tid  = threadIdx.x;
    const int lane = tid & 63;
    const int wave = tid >> 6;

    for (int e = tid; e < ED; e += 256) routerLocal[e] = 0.f;
    __syncthreads();

    const int t0 = blockIdx.x * TOKS_PER_BLK;
    for (int t = t0; t < t0 + TOKS_PER_BLK; ++t) {
        const float* lrow = &OUT[(size_t)t * ED];
        float l[4];
#pragma unroll
        for (int i = 0; i < 4; ++i) l[i] = lrow[tid + i * 256];

        float m = fmaxf(fmaxf(l[0], l[1]), fmaxf(l[2], l[3]));
#pragma unroll
        for (int off = 32; off; off >>= 1) m = fmaxf(m, __shfl_xor(m, off));
        if (lane == 0) redMax[wave] = m;
        __syncthreads();
        m = fmaxf(fmaxf(redMax[0], redMax[1]), fmaxf(redMax[2], redMax[3]));

        float p[4]; float s = 0.f;
#pragma unroll
        for (int i = 0; i < 4; ++i) { p[i] = expf(l[i] - m); s += p[i]; }
#pragma unroll
        for (int off = 32; off; off >>= 1) s += __shfl_xor(s, off);
        if (lane == 0) redSum[wave] = s;

        float v1 = -1e30f, v2 = -1e30f; int i1 = 0x7fffffff, i2 = 0x7fffffff;
#pragma unroll
        for (int i = 0; i < 4; ++i) {
            const float v = l[i]; const int ix = tid + i * 256;
            if (better(v, ix, v1, i1)) { v2 = v1; i2 = i1; v1 = v; i1 = ix; }
            else if (better(v, ix, v2, i2)) { v2 = v; i2 = ix; }
        }
#pragma unroll
        for (int off = 32; off; off >>= 1) {
            const float ov1 = __shfl_xor(v1, off); const int oi1 = __shfl_xor(i1, off);
            const float ov2 = __shfl_xor(v2, off); const int oi2 = __shfl_xor(i2, off);
            if (better(ov1, oi1, v1, i1)) {
                float nv2; int ni2;
                if (better(v1, i1, ov2, oi2)) { nv2 = v1; ni2 = i1; }
                else { nv2 = ov2; ni2 = oi2; }
                v1 = ov1; i1 = oi1; v2 = nv2; i2 = ni2;
            } else if (better(ov1, oi1, v2, i2)) { v2 = ov1; i2 = oi1; }
        }
        if (lane == 0) { wV1[wave] = v1; wI1[wave] = i1; wV2[wave] = v2; wI2[wave] = i2; }
        __syncthreads();

        v1 = wV1[0]; i1 = wI1[0]; v2 = wV2[0]; i2 = wI2[0];
#pragma unroll
        for (int w = 1; w < 4; ++w) {
            const float ov1 = wV1[w]; const int oi1 = wI1[w];
            const float ov2 = wV2[w]; const int oi2 = wI2[w];
            if (better(ov1, oi1, v1, i1)) {
                float nv2; int ni2;
                if (better(v1, i1, ov2, oi2)) { nv2 = v1; ni2 = i1; }
                else { nv2 = ov2; ni2 = oi2; }
                v1 = ov1; i1 = oi1; v2 = nv2; i2 = ni2;
            } else if (better(ov1, oi1, v2, i2)) { v2 = ov1; i2 = oi1; }
        }
        const float stot = redSum[0] + redSum[1] + redSum[2] + redSum[3];
        const float inv = 1.f / stot;

#pragma unroll
        for (int i = 0; i < 4; ++i) routerLocal[tid + i * 256] += p[i] * inv;

        const float p1 = expf(v1 - m) * inv;
        const float p2 = expf(v2 - m) * inv;

        const int b = t >> 10;
        const float4* x1 = (const float4*)&X[((size_t)(b << 10) + i1) * ED];
        const float4* x2 = (const float4*)&X[((size_t)(b << 10) + i2) * ED];
        float4* yrow = (float4*)&OUT[(size_t)t * ED];
        const float4 a = x1[tid];
        const float4 c = x2[tid];
        float4 r;
        r.x = fmaf(p1, a.x, p2 * c.x);
        r.y = fmaf(p1, a.y, p2 * c.y);
        r.z = fmaf(p1, a.z, p2 * c.z);
        r.w = fmaf(p1, a.w, p2 * c.w);
        yrow[tid] = r;

        if (tid == 0) { atomicAdd(&counts[i1], 1); atomicAdd(&counts[i2], 1); }
        __syncthreads();
    }

    for (int e = tid; e < ED; e += 256) atomicAdd(&router_sum[e], routerLocal[e]);
}

__global__ __launch_bounds__(256) void aux_kernel(const float* __restrict__ router_sum,
                                                  const int* __restrict__ counts,
                                                  float* __restrict__ out) {
    __shared__ float red[4];
    const int tid = threadIdx.x;
    float s = 0.f;
    for (int e = tid; e < ED; e += 256)
        s += (router_sum[e] * (1.f / 8192.f)) * ((float)counts[e] * (1.f / 16384.f));
#pragma unroll
    for (int off = 32; off; off >>= 1) s += __shfl_xor(s, off);
    if ((tid & 63) == 0) red[tid >> 6] = s;
    __syncthreads();
    if (tid == 0) out[(size_t)MTOK * ED] = 0.01f * 1024.f * (red[0] + red[1] + red[2] + red[3]);
}

// ---------------- launch ----------------
extern "C" void kernel_launch(void* const* d_in, const int* in_sizes, int n_in,
                              void* d_out, int out_size, void* d_ws, size_t ws_size,
                              hipStream_t stream) {
    const float* X = (const float*)d_in[0];   // (B,S,D) fp32
    const float* W = (const float*)d_in[1];   // (E,D)  fp32
    float* out = (float*)d_out;

    // ws: [Xfrag hi 16MB][Xfrag lo 16MB][Wfrag hi 2MB][Wfrag lo 2MB][dot 256B][counts 4KB]
    // router partial[2048][1024] (8MB) aliases Xfrag-hi (dead after GEMM).
    const size_t WS_NEED = (size_t)MTOK * ED * 2 * sizeof(unsigned short)   // 32MB
                         + (size_t)ED * ED * 2 * sizeof(unsigned short)     // 4MB
                         + 64 * sizeof(float) + ED * sizeof(int);

    if (ws_size >= WS_NEED) {
        unsigned short* Xfh = (unsigned short*)d_ws;
        unsigned short* Xfl = Xfh + (size_t)MTOK * ED;
        unsigned short* Wfh = Xfl + (size_t)MTOK * ED;
        unsigned short* Wfl = Wfh + (size_t)ED * ED;
        float* dotPartial   = (float*)(Wfl + (size_t)ED * ED);   // 64 floats
        int*   counts       = (int*)(dotPartial + 64);           // 1024 ints
        float* partial      = (float*)Xfh;                       // alias (dead after GEMM)

        hipMemsetAsync(counts, 0, ED * sizeof(int), stream);
        frag_kernel<<<4096, 256, 0, stream>>>(X, Xfh, Xfl);      // 16384 tasks
        frag_kernel<<<512, 256, 0, stream>>>(W, Wfh, Wfl);       // 2048 tasks
        gemm_frag_kernel<<<512, 256, 0, stream>>>(Xfh, Xfl, Wfh, Wfl, out);
        softmax_wave_kernel<<<MTOK / 4, 256, 0, stream>>>(X, out, partial, counts);
        aux1_kernel<<<64, 256, 0, stream>>>(partial, counts, dotPartial);
        aux2_kernel<<<1, 64, 0, stream>>>(dotPartial, out);
    } else {
        float* router_sum = (float*)d_ws;
        int*   counts     = (int*)((char*)d_ws + ED * sizeof(float));
        hipMemsetAsync(d_ws, 0, ED * (sizeof(float) + sizeof(int)), stream);
        dim3 ggrid(ED / BN, MTOK / BM);
        gemm_logits_kernel<<<ggrid, 256, 0, stream>>>(X, W, out);
        softmax_topk_y_kernel<<<MTOK / TOKS_PER_BLK, 256, 0, stream>>>(X, out, router_sum, counts);
        aux_kernel<<<1, 256, 0, stream>>>(router_sum, counts, out);
    }
}

// Round 13
// 95.199 us; speedup vs baseline: 1.1403x; 1.1403x over previous
//
#include <hip/hip_runtime.h>

#define MTOK 8192   // B*S tokens
#define ED   1024   // E == D == 1024

typedef short s16x8 __attribute__((ext_vector_type(8)));
typedef float f32x4 __attribute__((ext_vector_type(4)));
typedef int   i32x4 __attribute__((ext_vector_type(4)));
typedef unsigned short u16x4 __attribute__((ext_vector_type(4)));

__device__ __forceinline__ int cvtpk(float a, float b) {
    int r;
    asm("v_cvt_pk_bf16_f32 %0, %1, %2" : "=v"(r) : "v"(a), "v"(b));
    return r;
}

// pack f0|f1 (8 fp32) -> 8 bf16 hi + 8 bf16 lo (exact residual)
__device__ __forceinline__ void cvt_regs(const float4 f0, const float4 f1,
                                         s16x8* hi, s16x8* lo) {
    i32x4 h, l;
    h[0] = cvtpk(f0.x, f0.y); h[1] = cvtpk(f0.z, f0.w);
    h[2] = cvtpk(f1.x, f1.y); h[3] = cvtpk(f1.z, f1.w);
    l[0] = cvtpk(f0.x - __builtin_bit_cast(float, h[0] << 16),
                 f0.y - __builtin_bit_cast(float, h[0] & 0xffff0000));
    l[1] = cvtpk(f0.z - __builtin_bit_cast(float, h[1] << 16),
                 f0.w - __builtin_bit_cast(float, h[1] & 0xffff0000));
    l[2] = cvtpk(f1.x - __builtin_bit_cast(float, h[2] << 16),
                 f1.y - __builtin_bit_cast(float, h[2] & 0xffff0000));
    l[3] = cvtpk(f1.z - __builtin_bit_cast(float, h[3] << 16),
                 f1.w - __builtin_bit_cast(float, h[3] & 0xffff0000));
    *hi = __builtin_bit_cast(s16x8, h);
    *lo = __builtin_bit_cast(s16x8, l);
}

__device__ __forceinline__ void cvt_write(void* dstHi, void* dstLo,
                                          const float4 f0, const float4 f1) {
    s16x8 h, l;
    cvt_regs(f0, f1, &h, &l);
    *(s16x8*)dstHi = h;
    *(s16x8*)dstLo = l;
}

// ---------------- W -> fragment-major bf16 hi/lo (proven r11/r12) ----------------
// frag[rowblk][kstep][lane][8]: lane (fg=l>>4, fr=l&15) holds
//   W[rowblk*16+fr][kstep*32+fg*8 .. +8]
__global__ __launch_bounds__(256) void frag_kernel(
        const float* __restrict__ M,
        unsigned short* __restrict__ Fhi, unsigned short* __restrict__ Flo) {
    const int task = blockIdx.x * 4 + (threadIdx.x >> 6);
    const int lane = threadIdx.x & 63;
    const int rowblk = task >> 5;
    const int kstep  = task & 31;
    const float* src = M + (size_t)(rowblk * 16 + (lane & 15)) * ED
                         + kstep * 32 + (lane >> 4) * 8;
    const float4 f0 = *(const float4*)src;
    const float4 f1 = *(const float4*)(src + 4);
    const size_t o = ((size_t)task * 64 + lane) * 8;
    cvt_write(&Fhi[o], &Flo[o], f0, f1);
}

__device__ __forceinline__ bool better(float v, int i, float bv, int bi) {
    return (v > bv) || (v == bv && i < bi);
}

// ---------------- fused GEMM + softmax + top2 + y + router ----------------
// Block = 32 tokens x ALL 1024 experts (full logit rows -> no logits round-trip).
// 512 threads = 8 waves; wave w owns cols w*128..+128 (8 colblks x 2 rowblks).
// A: X fp32 per-lane load + cvt-in-reg (24 VALU vs 96 MFMA per wave-step).
// B: fragment-major Wfrag global->regs, double-buffered (L2-resident, all
// blocks on an XCD stream the same 4 MB). Epilogue: acc->LDS[32][1024] (128KB),
// in-LDS wave softmax (proven r3 logic), y direct, router block-reduce via LDS.
__global__ __launch_bounds__(512, 2) void moe_fused_kernel(
        const float* __restrict__ X,
        const unsigned short* __restrict__ Wfh, const unsigned short* __restrict__ Wfl,
        float* __restrict__ OUT, float* __restrict__ partial,
        int* __restrict__ counts) {
    __shared__ float L[32 * 1024];   // 128 KB (proven WG size per m201)

    const int tid  = threadIdx.x;
    const int lane = tid & 63;
    const int w    = tid >> 6;        // wave 0..7
    const int fr   = lane & 15, fg = lane >> 4;
    const int tok0 = blockIdx.x * 32;

    // A source: lane reads X[tok0 + rb*16 + fr][t*32 + fg*8 .. +8]
    const float* gA = X + (size_t)(tok0 + fr) * ED + fg * 8;
    // B source: wave w covers W rowblks w*8 .. w*8+7
    const unsigned short* gBh = Wfh + (size_t)(w * 8) * 16384 + lane * 8;
    const unsigned short* gBl = Wfl + (size_t)(w * 8) * 16384 + lane * 8;

    f32x4 acc[2][8] = {};
    s16x8 ah[2], al[2];
    s16x8 bh0[8], bl0[8], bh1[8], bl1[8];

#define LOADA(T)                                                        \
    _Pragma("unroll")                                                   \
    for (int rb = 0; rb < 2; ++rb) {                                    \
        const float* s = gA + (size_t)(rb * 16) * ED + (T) * 32;        \
        const float4 f0 = *(const float4*)s;                            \
        const float4 f1 = *(const float4*)(s + 4);                      \
        cvt_regs(f0, f1, &ah[rb], &al[rb]);                             \
    }

#define LOADB(S, T)                                                     \
    _Pragma("unroll")                                                   \
    for (int cb = 0; cb < 8; ++cb) {                                    \
        bh##S[cb] = *(const s16x8*)(gBh + cb * 16384 + (T) * 512);      \
        bl##S[cb] = *(const s16x8*)(gBl + cb * 16384 + (T) * 512);      \
    }

#define MFMAB(S)                                                        \
    _Pragma("unroll")                                                   \
    for (int rb = 0; rb < 2; ++rb)                                      \
        _Pragma("unroll")                                               \
        for (int cb = 0; cb < 8; ++cb) {                                \
            acc[rb][cb] = __builtin_amdgcn_mfma_f32_16x16x32_bf16(ah[rb], bh##S[cb], acc[rb][cb], 0, 0, 0); \
            acc[rb][cb] = __builtin_amdgcn_mfma_f32_16x16x32_bf16(ah[rb], bl##S[cb], acc[rb][cb], 0, 0, 0); \
            acc[rb][cb] = __builtin_amdgcn_mfma_f32_16x16x32_bf16(al[rb], bh##S[cb], acc[rb][cb], 0, 0, 0); \
        }

    LOADA(0);
    LOADB(0, 0);
    for (int t2 = 0; t2 < 32; t2 += 2) {
        LOADB(1, t2 + 1);             // t2+1 <= 31 always
        MFMAB(0);                      // consumes ah (step t2)
        LOADA(t2 + 1);                 // safe: ah dead after MFMAB(0)
        if (t2 + 2 < 32) LOADB(0, t2 + 2);
        MFMAB(1);
        if (t2 + 2 < 32) LOADA(t2 + 2);
    }
#undef LOADA
#undef LOADB
#undef MFMAB

    // ---- logits -> LDS ----
#pragma unroll
    for (int rb = 0; rb < 2; ++rb)
#pragma unroll
        for (int cb = 0; cb < 8; ++cb)
#pragma unroll
            for (int r = 0; r < 4; ++r)
                L[(rb * 16 + fg * 4 + r) * 1024 + w * 128 + cb * 16 + fr] = acc[rb][cb][r];
    __syncthreads();

    // ---- per-wave softmax/top2/y over 4 tokens (proven r3 logic, LDS src) ----
    float4 rl[4];   // router accumulator: rl[i] covers elems i*256 + lane*4 ..+3
#pragma unroll
    for (int i = 0; i < 4; ++i) rl[i] = make_float4(0.f, 0.f, 0.f, 0.f);

    for (int q = 0; q < 4; ++q) {
        const int tk = w * 4 + q;
        float4 p[4];
#pragma unroll
        for (int i = 0; i < 4; ++i)
            p[i] = *(const float4*)&L[tk * 1024 + i * 256 + lane * 4];

        float v1 = -1e30f, v2 = -1e30f; int i1 = 0x7fffffff, i2 = 0x7fffffff;
#pragma unroll
        for (int i = 0; i < 4; ++i) {
            const float vv[4] = {p[i].x, p[i].y, p[i].z, p[i].w};
#pragma unroll
            for (int c = 0; c < 4; ++c) {
                const int e = 256 * i + 4 * lane + c;
                const float v = vv[c];
                if (better(v, e, v1, i1)) { v2 = v1; i2 = i1; v1 = v; i1 = e; }
                else if (better(v, e, v2, i2)) { v2 = v; i2 = e; }
            }
        }
#pragma unroll
        for (int off = 32; off; off >>= 1) {
            const float ov1 = __shfl_xor(v1, off); const int oi1 = __shfl_xor(i1, off);
            const float ov2 = __shfl_xor(v2, off); const int oi2 = __shfl_xor(i2, off);
            if (better(ov1, oi1, v1, i1)) {
                float nv2; int ni2;
                if (better(v1, i1, ov2, oi2)) { nv2 = v1; ni2 = i1; }
                else { nv2 = ov2; ni2 = oi2; }
                v1 = ov1; i1 = oi1; v2 = nv2; i2 = ni2;
            } else if (better(ov1, oi1, v2, i2)) { v2 = ov1; i2 = oi1; }
        }
        const float m = v1;   // top1 IS the row max

        float s = 0.f;
#pragma unroll
        for (int i = 0; i < 4; ++i) {
            p[i].x = __expf(p[i].x - m); p[i].y = __expf(p[i].y - m);
            p[i].z = __expf(p[i].z - m); p[i].w = __expf(p[i].w - m);
            s += p[i].x + p[i].y + p[i].z + p[i].w;
        }
#pragma unroll
        for (int off = 32; off; off >>= 1) s += __shfl_xor(s, off);
        const float inv = 1.f / s;

#pragma unroll
        for (int i = 0; i < 4; ++i) {
            rl[i].x += p[i].x * inv; rl[i].y += p[i].y * inv;
            rl[i].z += p[i].z * inv; rl[i].w += p[i].w * inv;
        }

        const float p1 = inv;                    // exp(v1-m)=1
        const float p2 = __expf(v2 - m) * inv;
        const int tglob = tok0 + tk;
        const int b = tglob >> 10;
        const float4* x1 = (const float4*)&X[((size_t)(b << 10) + i1) * ED];
        const float4* x2 = (const float4*)&X[((size_t)(b << 10) + i2) * ED];
        float4* yrow = (float4*)&OUT[(size_t)tglob * ED];
#pragma unroll
        for (int i = 0; i < 4; ++i) {
            const int idx = lane + 64 * i;
            const float4 a = x1[idx];
            const float4 c = x2[idx];
            float4 r;
            r.x = fmaf(p1, a.x, p2 * c.x);
            r.y = fmaf(p1, a.y, p2 * c.y);
            r.z = fmaf(p1, a.z, p2 * c.z);
            r.w = fmaf(p1, a.w, p2 * c.w);
            yrow[idx] = r;
        }
        if (lane == 0) { atomicAdd(&counts[i1], 1); atomicAdd(&counts[i2], 1); }
    }

    // ---- router partial: wave writes its 4-token sums into its OWN rows ----
    // row (w*4+i) col range [256i,256i+256) <- rl[i]  (rows fully consumed above)
#pragma unroll
    for (int i = 0; i < 4; ++i)
        *(float4*)&L[(w * 4 + i) * 1024 + i * 256 + lane * 4] = rl[i];
    __syncthreads();

    // block reduce: thread handles elems {2tid, 2tid+1}; contribution for elem e
    // sits at rows {4*ww + (e>>8)}, col e.
    {
        const int e = tid * 2;
        const int i = e >> 8;
        float s0 = 0.f, s1 = 0.f;
#pragma unroll
        for (int ww = 0; ww < 8; ++ww) {
            s0 += L[(ww * 4 + i) * 1024 + e];
            s1 += L[(ww * 4 + i) * 1024 + e + 1];
        }
        partial[(size_t)blockIdx.x * 1024 + e]     = s0;
        partial[(size_t)blockIdx.x * 1024 + e + 1] = s1;
    }
}

// ---------------- aux: deterministic two-stage reduction (P=256 partials) ------
__global__ __launch_bounds__(256) void aux1_kernel(const float* __restrict__ partial,
                                                   const int* __restrict__ counts,
                                                   float* __restrict__ dotPartial) {
    __shared__ float red[16][16];
    const int tid = threadIdx.x;
    const int el  = tid & 15;
    const int ch  = tid >> 4;          // 16 chunks x 16 partials
    const int e   = blockIdx.x * 16 + el;
    float s = 0.f;
    for (int k = 0; k < 16; ++k)
        s += partial[(size_t)(ch * 16 + k) * 1024 + e];
    red[ch][el] = s;
    __syncthreads();
    if (tid < 16) {
        float rs = 0.f;
#pragma unroll
        for (int c = 0; c < 16; ++c) rs += red[c][tid];
        float val = rs * (float)counts[blockIdx.x * 16 + tid];
#pragma unroll
        for (int off = 8; off; off >>= 1) val += __shfl_xor(val, off);
        if (tid == 0) dotPartial[blockIdx.x] = val;
    }
}

__global__ void aux2_kernel(const float* __restrict__ dotPartial, float* __restrict__ out) {
    const int lane = threadIdx.x;
    float v = dotPartial[lane];
#pragma unroll
    for (int off = 32; off; off >>= 1) v += __shfl_xor(v, off);
    if (lane == 0)
        out[(size_t)MTOK * ED] = v * (0.01f * 1024.f / (8192.f * 16384.f));
}

// ---------------- fp32 fallback path (proven round-1) ----------------
#define BM 128
#define BN 128
#define BK 32
#define LDA (BM + 4)
#define LDB (BN + 4)

__global__ __launch_bounds__(256) void gemm_logits_kernel(const float* __restrict__ X,
                                                          const float* __restrict__ W,
                                                          float* __restrict__ C) {
    __shared__ float As[BK][LDA];
    __shared__ float Bs[BK][LDB];
    const int bm  = blockIdx.y * BM;
    const int bn  = blockIdx.x * BN;
    const int tid = threadIdx.x;
    const int tx  = tid & 15;
    const int ty  = tid >> 4;
    const int lr  = tid >> 3;
    const int lc  = (tid & 7) << 2;

    float acc[8][8];
#pragma unroll
    for (int i = 0; i < 8; ++i)
#pragma unroll
        for (int j = 0; j < 8; ++j) acc[i][j] = 0.f;

    for (int k0 = 0; k0 < ED; k0 += BK) {
#pragma unroll
        for (int i = 0; i < 4; ++i) {
            const int r = lr + i * 32;
            float4 va = *(const float4*)&X[(size_t)(bm + r) * ED + k0 + lc];
            As[lc + 0][r] = va.x; As[lc + 1][r] = va.y;
            As[lc + 2][r] = va.z; As[lc + 3][r] = va.w;
            float4 vb = *(const float4*)&W[(size_t)(bn + r) * ED + k0 + lc];
            Bs[lc + 0][r] = vb.x; Bs[lc + 1][r] = vb.y;
            Bs[lc + 2][r] = vb.z; Bs[lc + 3][r] = vb.w;
        }
        __syncthreads();
#pragma unroll
        for (int kk = 0; kk < BK; ++kk) {
            float a[8], b[8];
            *(float4*)&a[0] = *(const float4*)&As[kk][ty * 8];
            *(float4*)&a[4] = *(const float4*)&As[kk][ty * 8 + 4];
            *(float4*)&b[0] = *(const float4*)&Bs[kk][tx * 8];
            *(float4*)&b[4] = *(const float4*)&Bs[kk][tx * 8 + 4];
#pragma unroll
            for (int i = 0; i < 8; ++i)
#pragma unroll
                for (int j = 0; j < 8; ++j)
                    acc[i][j] = fmaf(a[i], b[j], acc[i][j]);
        }
        __syncthreads();
    }
#pragma unroll
    for (int i = 0; i < 8; ++i) {
        const int r = bm + ty * 8 + i;
        float4* dst = (float4*)&C[(size_t)r * ED + bn + tx * 8];
        dst[0] = make_float4(acc[i][0], acc[i][1], acc[i][2], acc[i][3]);
        dst[1] = make_float4(acc[i][4], acc[i][5], acc[i][6], acc[i][7]);
    }
}

#define TOKS_PER_BLK 16
__global__ __launch_bounds__(256) void softmax_topk_y_kernel(
        const float* __restrict__ X, float* __restrict__ OUT,
        float* __restrict__ router_sum, int* __restrict__ counts) {
    __shared__ float routerLocal[ED];
    __shared__ float redMax[4];
    __shared__ float redSum[4];
    __shared__ float wV1[4]; __shared__ int wI1[4];
    __shared__ float wV2[4]; __shared__ int wI2[4];

    const int tid  = threadIdx.x;
    const int lane = tid & 63;
    const int wave = tid >> 6;

    for (int e = tid; e < ED; e += 256) routerLocal[e] = 0.f;
    __syncthreads();

    const int t0 = blockIdx.x * TOKS_PER_BLK;
    for (int t = t0; t < t0 + TOKS_PER_BLK; ++t) {
        const float* lrow = &OUT[(size_t)t * ED];
        float l[4];
#pragma unroll
        for (int i = 0; i < 4; ++i) l[i] = lrow[tid + i * 256];

        float m = fmaxf(fmaxf(l[0], l[1]), fmaxf(l[2], l[3]));
#pragma unroll
        for (int off = 32; off; off >>= 1) m = fmaxf(m, __shfl_xor(m, off));
        if (lane == 0) redMax[wave] = m;
        __syncthreads();
        m = fmaxf(fmaxf(redMax[0], redMax[1]), fmaxf(redMax[2], redMax[3]));

        float p[4]; float s = 0.f;
#pragma unroll
        for (int i = 0; i < 4; ++i) { p[i] = expf(l[i] - m); s += p[i]; }
#pragma unroll
        for (int off = 32; off; off >>= 1) s += __shfl_xor(s, off);
        if (lane == 0) redSum[wave] = s;

        float v1 = -1e30f, v2 = -1e30f; int i1 = 0x7fffffff, i2 = 0x7fffffff;
#pragma unroll
        for (int i = 0; i < 4; ++i) {
            const float v = l[i]; const int ix = tid + i * 256;
            if (better(v, ix, v1, i1)) { v2 = v1; i2 = i1; v1 = v; i1 = ix; }
            else if (better(v, ix, v2, i2)) { v2 = v; i2 = ix; }
        }
#pragma unroll
        for (int off = 32; off; off >>= 1) {
            const float ov1 = __shfl_xor(v1, off); const int oi1 = __shfl_xor(i1, off);
            const float ov2 = __shfl_xor(v2, off); const int oi2 = __shfl_xor(i2, off);
            if (better(ov1, oi1, v1, i1)) {
                float nv2; int ni2;
                if (better(v1, i1, ov2, oi2)) { nv2 = v1; ni2 = i1; }
                else { nv2 = ov2; ni2 = oi2; }
                v1 = ov1; i1 = oi1; v2 = nv2; i2 = ni2;
            } else if (better(ov1, oi1, v2, i2)) { v2 = ov1; i2 = oi1; }
        }
        if (lane == 0) { wV1[wave] = v1; wI1[wave] = i1; wV2[wave] = v2; wI2[wave] = i2; }
        __syncthreads();

        v1 = wV1[0]; i1 = wI1[0]; v2 = wV2[0]; i2 = wI2[0];
#pragma unroll
        for (int w = 1; w < 4; ++w) {
            const float ov1 = wV1[w]; const int oi1 = wI1[w];
            const float ov2 = wV2[w]; const int oi2 = wI2[w];
            if (better(ov1, oi1, v1, i1)) {
                float nv2; int ni2;
                if (better(v1, i1, ov2, oi2)) { nv2 = v1; ni2 = i1; }
                else { nv2 = ov2; ni2 = oi2; }
                v1 = ov1; i1 = oi1; v2 = nv2; i2 = ni2;
            } else if (better(ov1, oi1, v2, i2)) { v2 = ov1; i2 = oi1; }
        }
        const float stot = redSum[0] + redSum[1] + redSum[2] + redSum[3];
        const float inv = 1.f / stot;

#pragma unroll
        for (int i = 0; i < 4; ++i) routerLocal[tid + i * 256] += p[i] * inv;

        const float p1 = expf(v1 - m) * inv;
        const float p2 = expf(v2 - m) * inv;

        const int b = t >> 10;
        const float4* x1 = (const float4*)&X[((size_t)(b << 10) + i1) * ED];
        const float4* x2 = (const float4*)&X[((size_t)(b << 10) + i2) * ED];
        float4* yrow = (float4*)&OUT[(size_t)t * ED];
        const float4 a = x1[tid];
        const float4 c = x2[tid];
        float4 r;
        r.x = fmaf(p1, a.x, p2 * c.x);
        r.y = fmaf(p1, a.y, p2 * c.y);
        r.z = fmaf(p1, a.z, p2 * c.z);
        r.w = fmaf(p1, a.w, p2 * c.w);
        yrow[tid] = r;

        if (tid == 0) { atomicAdd(&counts[i1], 1); atomicAdd(&counts[i2], 1); }
        __syncthreads();
    }

    for (int e = tid; e < ED; e += 256) atomicAdd(&router_sum[e], routerLocal[e]);
}

__global__ __launch_bounds__(256) void aux_kernel(const float* __restrict__ router_sum,
                                                  const int* __restrict__ counts,
                                                  float* __restrict__ out) {
    __shared__ float red[4];
    const int tid = threadIdx.x;
    float s = 0.f;
    for (int e = tid; e < ED; e += 256)
        s += (router_sum[e] * (1.f / 8192.f)) * ((float)counts[e] * (1.f / 16384.f));
#pragma unroll
    for (int off = 32; off; off >>= 1) s += __shfl_xor(s, off);
    if ((tid & 63) == 0) red[tid >> 6] = s;
    __syncthreads();
    if (tid == 0) out[(size_t)MTOK * ED] = 0.01f * 1024.f * (red[0] + red[1] + red[2] + red[3]);
}

// ---------------- launch ----------------
extern "C" void kernel_launch(void* const* d_in, const int* in_sizes, int n_in,
                              void* d_out, int out_size, void* d_ws, size_t ws_size,
                              hipStream_t stream) {
    const float* X = (const float*)d_in[0];   // (B,S,D) fp32
    const float* W = (const float*)d_in[1];   // (E,D)  fp32
    float* out = (float*)d_out;

    // ws: [Wfrag hi 2MB][Wfrag lo 2MB][partial 256x1024 f32 1MB][dot 256B][counts 4KB]
    const size_t WS_NEED = (size_t)ED * ED * 2 * sizeof(unsigned short)
                         + (size_t)256 * 1024 * sizeof(float)
                         + 64 * sizeof(float) + ED * sizeof(int);

    if (ws_size >= WS_NEED) {
        unsigned short* Wfh = (unsigned short*)d_ws;
        unsigned short* Wfl = Wfh + (size_t)ED * ED;
        float* partial      = (float*)(Wfl + (size_t)ED * ED);   // [256][1024]
        float* dotPartial   = partial + (size_t)256 * 1024;      // 64 floats
        int*   counts       = (int*)(dotPartial + 64);           // 1024 ints

        hipMemsetAsync(counts, 0, ED * sizeof(int), stream);
        frag_kernel<<<512, 256, 0, stream>>>(W, Wfh, Wfl);       // 2048 tasks
        moe_fused_kernel<<<MTOK / 32, 512, 0, stream>>>(X, Wfh, Wfl, out, partial, counts);
        aux1_kernel<<<64, 256, 0, stream>>>(partial, counts, dotPartial);
        aux2_kernel<<<1, 64, 0, stream>>>(dotPartial, out);
    } else {
        float* router_sum = (float*)d_ws;
        int*   counts     = (int*)((char*)d_ws + ED * sizeof(float));
        hipMemsetAsync(d_ws, 0, ED * (sizeof(float) + sizeof(int)), stream);
        dim3 ggrid(ED / BN, MTOK / BM);
        gemm_logits_kernel<<<ggrid, 256, 0, stream>>>(X, W, out);
        softmax_topk_y_kernel<<<MTOK / TOKS_PER_BLK, 256, 0, stream>>>(X, out, router_sum, counts);
        aux_kernel<<<1, 256, 0, stream>>>(router_sum, counts, out);
    }
}